// Round 1
// baseline (403.604 us; speedup 1.0000x reference)
//
#include <hip/hip_runtime.h>
#include <hip/hip_fp16.h>

// out[r] = sum_{e: row[e]==r} val[e] * embs[col[e]]
// N_NODES = 100000, N_EDGES = 3200000, D = 128, fp32.
//
// Pipeline (5 dispatches):
//   memset      : cbcnt/gcur/done (2 KB)
//   k_hist_conv : [hist blocks] coarse 512-row bucket counts + last-block scan
//                 [conv blocks] embs fp32 -> fp16
//   k_part1     : LDS-staged partition, coalesced runs into tmp1 (= d_out alias)
//   k_part2     : 1024 thr/block (was 256: 196 blocks x 4 waves was the
//                 occupancy hole), per-bucket row sort -> pcv + CSR
//   k_rows_h    : one wave per row, software-pipelined pcv prefetch,
//                 nontemporal pcv/out so streams don't evict embs16 from L2.

#define D_FEAT 128
#define CSHIFT 9             // 512 rows per coarse bucket
#define CROWS 512
#define MAXNBC 256
#define EPT 16
#define BLK 256
#define EPB (BLK * EPT)      // 4096 edges per partition block
#define BLK2 1024            // k_part2 block size

// ---- nontemporal helpers (builtin needs scalar/vector types, not HIP structs)
__device__ __forceinline__ int2 nt_load_int2(const int2* p) {
    long long v = __builtin_nontemporal_load(reinterpret_cast<const long long*>(p));
    int2 r;
    r.x = (int)(unsigned int)(v & 0xFFFFFFFFll);
    r.y = (int)(unsigned int)(((unsigned long long)v) >> 32);
    return r;
}
__device__ __forceinline__ void nt_store_f2(float* base, float2 v) {
    unsigned long long u = ((unsigned long long)__float_as_uint(v.y) << 32) |
                           (unsigned long long)__float_as_uint(v.x);
    __builtin_nontemporal_store((long long)u, reinterpret_cast<long long*>(base));
}

// ---------- fused: coarse histogram (+last-block scan) and embs fp32->fp16 ----------
__global__ __launch_bounds__(256) void k_hist_conv(const int* __restrict__ row,
                                                   int* __restrict__ cbcnt,
                                                   int* __restrict__ cstart,
                                                   int* __restrict__ done,
                                                   int n_edges, int nbc, int hist_blocks,
                                                   const float* __restrict__ embs,
                                                   __half* __restrict__ embs16,
                                                   int n_f4pairs) {
    int tid = threadIdx.x;
    if ((int)blockIdx.x >= hist_blocks) {
        // ---- conv part: 2x float4 (8 floats) per thread ----
        int i = (blockIdx.x - hist_blocks) * 256 + tid;
        if (i >= n_f4pairs) return;
        const float4* src = reinterpret_cast<const float4*>(embs) + (size_t)i * 2;
        float4 f0 = src[0];
        float4 f1 = src[1];
        __half2* dst = reinterpret_cast<__half2*>(embs16) + (size_t)i * 4;
        dst[0] = __floats2half2_rn(f0.x, f0.y);
        dst[1] = __floats2half2_rn(f0.z, f0.w);
        dst[2] = __floats2half2_rn(f1.x, f1.y);
        dst[3] = __floats2half2_rn(f1.z, f1.w);
        return;
    }
    // ---- hist part ----
    __shared__ int l[MAXNBC];
    __shared__ int s[256];
    __shared__ int lastflag;
    for (int j = tid; j < nbc; j += 256) l[j] = 0;
    __syncthreads();
    int base = blockIdx.x * EPB;
#pragma unroll
    for (int k = 0; k < EPT; ++k) {
        int e = base + k * 256 + tid;
        if (e < n_edges) atomicAdd(&l[__builtin_nontemporal_load(row + e) >> CSHIFT], 1);
    }
    __syncthreads();
    for (int j = tid; j < nbc; j += 256)
        if (l[j]) atomicAdd(&cbcnt[j], l[j]);
    __threadfence();
    if (tid == 0) lastflag = (atomicAdd(done, 1) == hist_blocks - 1);
    __syncthreads();
    if (!lastflag) return;
    // ---- last hist block: exclusive scan of cbcnt -> cstart ----
    int v = (tid < nbc) ? __hip_atomic_load(&cbcnt[tid], __ATOMIC_RELAXED,
                                            __HIP_MEMORY_SCOPE_AGENT) : 0;
    s[tid] = v;
    __syncthreads();
    for (int off = 1; off < 256; off <<= 1) {
        int u = (tid >= off) ? s[tid - off] : 0;
        __syncthreads();
        s[tid] += u;
        __syncthreads();
    }
    if (tid < nbc) {
        cstart[tid] = s[tid] - v;
        if (tid == nbc - 1) cstart[nbc] = s[tid];
    }
}

// ---------- pass 1: LDS-staged coarse partition, coalesced run writes ----------
__global__ __launch_bounds__(BLK) void k_part1(const int* __restrict__ row,
                                               const int* __restrict__ col,
                                               const float* __restrict__ val,
                                               const int* __restrict__ cstart,
                                               int* __restrict__ gcur,
                                               int2* __restrict__ tmp1,
                                               int n_edges, int nbc) {
    __shared__ int2 stage[EPB];                 // 32 KB
    __shared__ int lcnt[MAXNBC], lstart[MAXNBC + 1], lcur[MAXNBC], lbase[MAXNBC];
    __shared__ int ssc[256];
    int tid = threadIdx.x;
    for (int j = tid; j < nbc; j += BLK) { lcnt[j] = 0; lcur[j] = 0; }
    __syncthreads();

    int base = blockIdx.x * EPB;
    int ne = n_edges - base; if (ne > EPB) ne = EPB;

    int r[EPT], c[EPT]; float v[EPT];
#pragma unroll
    for (int k = 0; k < EPT; ++k) {
        int e = base + k * BLK + tid;
        r[k] = -1;
        if (e < n_edges) {
            r[k] = __builtin_nontemporal_load(row + e);
            c[k] = __builtin_nontemporal_load(col + e);
            v[k] = __builtin_nontemporal_load(val + e);
            atomicAdd(&lcnt[r[k] >> CSHIFT], 1);
        }
    }
    __syncthreads();
    // exclusive scan of lcnt
    int cv = (tid < nbc) ? lcnt[tid] : 0;
    ssc[tid] = cv;
    __syncthreads();
    for (int off = 1; off < 256; off <<= 1) {
        int u = (tid >= off) ? ssc[tid - off] : 0;
        __syncthreads();
        ssc[tid] += u;
        __syncthreads();
    }
    if (tid < nbc) {
        lstart[tid] = ssc[tid] - cv;
        if (cv) lbase[tid] = cstart[tid] + atomicAdd(&gcur[tid], cv);
        if (tid == nbc - 1) lstart[nbc] = ssc[tid];
    }
    __syncthreads();
    // place into LDS stage, bucket-sorted
#pragma unroll
    for (int k = 0; k < EPT; ++k) {
        if (r[k] >= 0) {
            int b = r[k] >> CSHIFT;
            int slot = lstart[b] + atomicAdd(&lcur[b], 1);
            stage[slot] = make_int2(((r[k] & (CROWS - 1)) << 17) | c[k],
                                    __float_as_int(v[k]));
        }
    }
    __syncthreads();
    // coalesced write-out: contiguous LDS -> contiguous global runs per bucket
    for (int i = tid; i < ne; i += BLK) {
        int lo = 0, hi = nbc;
        while (hi - lo > 1) {                    // upper_bound(lstart, i) - 1
            int mid = (lo + hi) >> 1;
            if (lstart[mid] <= i) lo = mid; else hi = mid;
        }
        tmp1[lbase[lo] + (i - lstart[lo])] = stage[i];
    }
}

// ---------- pass 2: per-coarse-bucket row sort -> pcv + CSR (1024 threads) ----------
__global__ __launch_bounds__(BLK2) void k_part2(const int2* __restrict__ tmp1,
                                                const int* __restrict__ cstart,
                                                int2* __restrict__ pcv,
                                                int* __restrict__ row_start,
                                                int* __restrict__ row_cnt,
                                                int n_nodes) {
    __shared__ int rcnt[CROWS], rstart[CROWS], rcur[CROWS], ps[CROWS];
    int b = blockIdx.x, tid = threadIdx.x;
    int base = cstart[b], end = cstart[b + 1];

    for (int j = tid; j < CROWS; j += BLK2) { rcnt[j] = 0; rcur[j] = 0; }
    __syncthreads();
    for (int i = base + tid; i < end; i += BLK2) {
        int lr = ((unsigned)tmp1[i].x) >> 17;
        atomicAdd(&rcnt[lr], 1);
    }
    __syncthreads();
    // exclusive scan over 512 counts (first 512 threads, Hillis-Steele)
    int v = 0;
    if (tid < CROWS) { v = rcnt[tid]; ps[tid] = v; }
    __syncthreads();
    for (int off = 1; off < CROWS; off <<= 1) {
        int u = 0;
        if (tid < CROWS && tid >= off) u = ps[tid - off];
        __syncthreads();
        if (tid < CROWS) ps[tid] += u;
        __syncthreads();
    }
    if (tid < CROWS) rstart[tid] = ps[tid] - v;
    __syncthreads();
    // emit CSR metadata
    if (tid < CROWS) {
        int gr = (b << CSHIFT) + tid;
        if (gr < n_nodes) {
            row_start[gr] = base + rstart[tid];
            row_cnt[gr]   = rcnt[tid];
        }
    }
    // scatter to row-sorted positions (block-private ~130 KB window, L2-hot)
    for (int i = base + tid; i < end; i += BLK2) {
        int2 p = tmp1[i];
        int lr = ((unsigned)p.x) >> 17;
        int pos = base + rstart[lr] + atomicAdd(&rcur[lr], 1);
        pcv[pos] = make_int2(p.x & 0x1FFFF, p.y);
    }
}

// ---------- accumulate: one wave per row, pipelined pcv prefetch ----------
__global__ __launch_bounds__(256) void k_rows_h(const int2* __restrict__ pcv,
                                                const int* __restrict__ row_start,
                                                const int* __restrict__ row_cnt,
                                                const __half2* __restrict__ eb,
                                                float* __restrict__ out, int n_nodes) {
    int gtid = blockIdx.x * blockDim.x + threadIdx.x;
    int r = gtid >> 6;
    int lane = threadIdx.x & 63;
    if (r >= n_nodes) return;

    int start = row_start[r];
    int cnt   = row_cnt[r];
    int end   = start + cnt;

    float2 acc = make_float2(0.f, 0.f);

    int i = start;
    int iend = start + (cnt & ~7);
    if (i < iend) {
        int2 p[8];
#pragma unroll
        for (int k = 0; k < 8; ++k) p[k] = nt_load_int2(&pcv[i + k]);
        i += 8;
        while (true) {
            __half2 h[8];
#pragma unroll
            for (int k = 0; k < 8; ++k) h[k] = eb[(size_t)p[k].x * 64 + lane];
            bool more = (i < iend);
            int2 pn[8];
            if (more) {
#pragma unroll
                for (int k = 0; k < 8; ++k) pn[k] = nt_load_int2(&pcv[i + k]);
            }
#pragma unroll
            for (int k = 0; k < 8; ++k) {
                float v = __int_as_float(p[k].y);
                float2 f = __half22float2(h[k]);
                acc.x += v * f.x;
                acc.y += v * f.y;
            }
            if (!more) break;
#pragma unroll
            for (int k = 0; k < 8; ++k) p[k] = pn[k];
            i += 8;
        }
    }
    for (; i < end; ++i) {
        int2 p = nt_load_int2(&pcv[i]);
        float v = __int_as_float(p.y);
        float2 f = __half22float2(eb[(size_t)p.x * 64 + lane]);
        acc.x += v * f.x;
        acc.y += v * f.y;
    }
    nt_store_f2(out + (size_t)r * D_FEAT + (size_t)lane * 2, acc);
}

// ---------- fallback: atomic scatter ----------
__global__ void gcn_scatter_atomic(const int* __restrict__ edge_row,
                                   const int* __restrict__ edge_col,
                                   const float* __restrict__ edge_val,
                                   const float* __restrict__ embs,
                                   float* __restrict__ out, int n_edges) {
    long long tid = (long long)blockIdx.x * blockDim.x + threadIdx.x;
    int sub = (int)(tid & 31);
    long long edge = tid >> 5;
    if (edge >= n_edges) return;
    int r = edge_row[edge];
    int c = edge_col[edge];
    float v = edge_val[edge];
    const float4* src = reinterpret_cast<const float4*>(embs + (size_t)c * D_FEAT);
    float4 m = src[sub];
    float* dst = out + (size_t)r * D_FEAT + (size_t)sub * 4;
    atomicAdd(dst + 0, m.x * v);
    atomicAdd(dst + 1, m.y * v);
    atomicAdd(dst + 2, m.z * v);
    atomicAdd(dst + 3, m.w * v);
}

extern "C" void kernel_launch(void* const* d_in, const int* in_sizes, int n_in,
                              void* d_out, int out_size, void* d_ws, size_t ws_size,
                              hipStream_t stream) {
    const int*   edge_row = (const int*)d_in[0];
    const int*   edge_col = (const int*)d_in[1];
    const float* edge_val = (const float*)d_in[2];
    const float* embs     = (const float*)d_in[3];
    float*       out      = (float*)d_out;

    const int n_edges = in_sizes[0];
    const int n_nodes = out_size / D_FEAT;
    const int nbc = (n_nodes + CROWS - 1) >> CSHIFT;

    // Workspace layout
    char* ws = (char*)d_ws;
    const size_t off_pcv       = 0;
    const size_t off_row_start = off_pcv + (size_t)n_edges * 8;
    const size_t off_row_cnt   = off_row_start + (size_t)n_nodes * 4;
    const size_t off_cbcnt     = off_row_cnt + (size_t)n_nodes * 4;   // cbcnt+gcur+done contiguous (one memset)
    const size_t off_gcur      = off_cbcnt + (size_t)MAXNBC * 4;
    const size_t off_done      = off_gcur + (size_t)MAXNBC * 4;
    const size_t off_cstart    = off_done + 16;
    const size_t off_embs16    = (off_cstart + (size_t)(MAXNBC + 1) * 4 + 15) & ~(size_t)15;
    const size_t full_ws       = off_embs16 + (size_t)n_nodes * D_FEAT * 2;

    // tmp1 aliases d_out (consumed by k_part2 before k_rows_h writes out).
    bool tmp_fits = ((size_t)n_edges * 8 <= (size_t)out_size * 4);
    bool packs_ok = (n_nodes <= 131072) && (nbc <= MAXNBC);  // 17-bit col, 9-bit lr

    if (ws_size < full_ws || !tmp_fits || !packs_ok) {
        hipMemsetAsync(d_out, 0, (size_t)out_size * sizeof(float), stream);
        long long total = (long long)n_edges * 32;
        int blocks = (int)((total + 255) / 256);
        gcn_scatter_atomic<<<blocks, 256, 0, stream>>>(edge_row, edge_col, edge_val,
                                                       embs, out, n_edges);
        return;
    }

    int2*   pcv       = (int2*)(ws + off_pcv);
    int*    row_start = (int*)(ws + off_row_start);
    int*    row_cnt   = (int*)(ws + off_row_cnt);
    int*    cbcnt     = (int*)(ws + off_cbcnt);
    int*    gcur      = (int*)(ws + off_gcur);
    int*    done      = (int*)(ws + off_done);
    int*    cstart    = (int*)(ws + off_cstart);
    __half* embs16    = (__half*)(ws + off_embs16);
    int2*   tmp1      = (int2*)d_out;

    // zero cbcnt + gcur + done in one shot
    hipMemsetAsync(cbcnt, 0, (size_t)MAXNBC * 8 + 16, stream);

    const int nchunks = (n_edges + EPB - 1) / EPB;
    const int nf4p = n_nodes * (D_FEAT / 8);       // 2x float4 per thread
    const int conv_blocks = (nf4p + 255) / 256;

    k_hist_conv<<<nchunks + conv_blocks, 256, 0, stream>>>(
        edge_row, cbcnt, cstart, done, n_edges, nbc, nchunks,
        embs, embs16, nf4p);
    k_part1<<<nchunks, BLK, 0, stream>>>(edge_row, edge_col, edge_val,
                                         cstart, gcur, tmp1, n_edges, nbc);
    k_part2<<<nbc, BLK2, 0, stream>>>(tmp1, cstart, pcv, row_start, row_cnt, n_nodes);

    long long rows_threads = (long long)n_nodes * 64;
    int rblocks = (int)((rows_threads + 255) / 256);
    k_rows_h<<<rblocks, 256, 0, stream>>>(pcv, row_start, row_cnt,
                                          (const __half2*)embs16, out, n_nodes);
}